// Round 11
// baseline (184.904 us; speedup 1.0000x reference)
//
#include <hip/hip_runtime.h>
#include <hip/hip_bf16.h>

// Problem constants
#define B_    2
#define C_    256
#define T_    4096
#define GRP   32
#define CPG   8
#define NH    4
#define CH    64
#define K3C   768
#define SPLIT 4
#define GSL   8          // group-norm slices per group
#define NSTAT (B_ * GRP * GSL)   // 512
#define NCVT  128
#define LOG2E 1.4426950408889634f

typedef __attribute__((ext_vector_type(8))) short bf16x8;
typedef __attribute__((ext_vector_type(4))) float f32x4;

#if __has_builtin(__builtin_amdgcn_exp2f)
#define EXP2(x) __builtin_amdgcn_exp2f(x)
#else
#define EXP2(x) exp2f(x)
#endif

__device__ __forceinline__ unsigned pk2(float a, float b) {
    __hip_bfloat162 h = __float22bfloat162_rn(make_float2(a, b));
    union { __hip_bfloat162 h2; unsigned u; } cv; cv.h2 = h;
    return cv.u;
}
__device__ __forceinline__ float bf2f(unsigned short u) {
    return __uint_as_float((unsigned)u << 16);
}

// ---------------------------------------------------------------------------
// Kernel 0: fused GroupNorm stats (blocks 0..511) + weight cvt (512..639).
// ---------------------------------------------------------------------------
__global__ __launch_bounds__(256) void pre_kernel(
    const float* __restrict__ x, float* __restrict__ stat,
    const float* __restrict__ qw, const float* __restrict__ pw,
    unsigned short* __restrict__ qwb, unsigned short* __restrict__ pwb) {
    int bid = blockIdx.x;
    int tid = threadIdx.x;
    if (bid < NSTAT) {
        int bg = bid >> 3, sl = bid & 7;
        const int SLN = CPG * T_ / GSL;        // 4096
        const float* xp = x + (size_t)bg * CPG * T_ + (size_t)sl * SLN;
        float s = 0.f, s2 = 0.f;
        for (int i = tid * 4; i < SLN; i += 1024) {
            float4 v = *(const float4*)&xp[i];
            s  += (v.x + v.y) + (v.z + v.w);
            s2 += (v.x * v.x + v.y * v.y) + (v.z * v.z + v.w * v.w);
        }
        for (int off = 32; off > 0; off >>= 1) {
            s  += __shfl_down(s,  off);
            s2 += __shfl_down(s2, off);
        }
        __shared__ float rs[4], rs2[4];
        int wid = tid >> 6;
        if ((tid & 63) == 0) { rs[wid] = s; rs2[wid] = s2; }
        __syncthreads();
        if (tid == 0) {
            stat[bid * 2]     = (rs[0] + rs[1]) + (rs[2] + rs[3]);
            stat[bid * 2 + 1] = (rs2[0] + rs2[1]) + (rs2[2] + rs2[3]);
        }
    } else {
        int i = (bid - NSTAT) * 256 + tid;
        const int n1 = K3C * C_ / 8;
        const float* src; unsigned short* dst;
        if (i < n1) { src = qw + 8 * i; dst = qwb + 8 * i; }
        else { int j = i - n1; src = pw + 8 * j; dst = pwb + 8 * j; }
        float4 a = *(const float4*)src;
        float4 b = *(const float4*)(src + 4);
        uint4 u;
        u.x = pk2(a.x, a.y); u.y = pk2(a.z, a.w);
        u.z = pk2(b.x, b.y); u.w = pk2(b.z, b.w);
        *(uint4*)dst = u;
    }
}

// ---------------------------------------------------------------------------
// Kernel 1: GroupNorm apply -> bf16 transposed xnT[b][t][c].
// ---------------------------------------------------------------------------
__global__ __launch_bounds__(256) void gn_apply_kernel(
    const float* __restrict__ x, const float* __restrict__ stat,
    const float* __restrict__ w, const float* __restrict__ b,
    unsigned short* __restrict__ xnT) {
    int bg = blockIdx.x, sl = blockIdx.y;
    int batch = bg / GRP, g = bg % GRP;
    const float* xp = x + (size_t)bg * CPG * T_;
    int tid = threadIdx.x;

    float s = 0.f, s2 = 0.f;
#pragma unroll
    for (int i = 0; i < GSL; ++i) {
        s  += stat[(bg * GSL + i) * 2];
        s2 += stat[(bg * GSL + i) * 2 + 1];
    }
    float inv_n = 1.f / (float)(CPG * T_);
    float mean = s * inv_n;
    float var  = s2 * inv_n - mean * mean;
    float inv  = rsqrtf(var + 1e-5f);

    float wv[8], bv[8];
#pragma unroll
    for (int j = 0; j < 8; j++) {
        float ww = w[g * CPG + j] * inv;
        wv[j] = ww;
        bv[j] = b[g * CPG + j] - mean * ww;
    }
    unsigned short* op = xnT + (size_t)batch * T_ * C_ + g * CPG;
    int t0 = sl * (T_ / GSL);
#pragma unroll
    for (int rep = 0; rep < 2; ++rep) {
        int t = t0 + rep * 256 + tid;
        float v[8];
#pragma unroll
        for (int j = 0; j < 8; j++) v[j] = xp[(size_t)j * T_ + t] * wv[j] + bv[j];
        uint4 u;
        u.x = pk2(v[0], v[1]); u.y = pk2(v[2], v[3]);
        u.z = pk2(v[4], v[5]); u.w = pk2(v[6], v[7]);
        *(uint4*)&op[(size_t)t * C_] = u;
    }
}

// ---------------------------------------------------------------------------
// Kernel 2: QKV GEMM.  W-tile staged in LDS once; X B-frags direct-global.
// grid(32,12,2), block 256.  Epilogue: q/k -> [t][c] (q pre-scaled), v -> v_d.
// ---------------------------------------------------------------------------
__global__ __launch_bounds__(256) void qkv_gemm_kernel(
    const unsigned short* __restrict__ Wb, const float* __restrict__ bias,
    const unsigned short* __restrict__ Xt, unsigned short* __restrict__ q_t,
    unsigned short* __restrict__ k_t, unsigned short* __restrict__ v_d) {
    int tb = blockIdx.x * 128;
    int by = blockIdx.y;
    int bz = blockIdx.z;
    int ob = by * 64;
    int tid = threadIdx.x;
    int l = tid & 15, oct = (tid >> 4) & 3, w = tid >> 6;

    __shared__ __align__(16) unsigned short SH[64 * 264];

#pragma unroll
    for (int j = 0; j < 8; ++j) {
        int idx = tid + 256 * j;
        int row = idx >> 5, ch = idx & 31;
        *(uint4*)&SH[row * 264 + ch * 8] =
            *(const uint4*)&Wb[(size_t)(ob + row) * C_ + ch * 8];
    }
    __syncthreads();

    const unsigned short* Xb = Xt + (size_t)bz * T_ * C_;

    f32x4 acc[4][2];
#pragma unroll
    for (int mf = 0; mf < 4; ++mf)
#pragma unroll
        for (int nf = 0; nf < 2; ++nf) acc[mf][nf] = (f32x4){0.f, 0.f, 0.f, 0.f};

#pragma unroll
    for (int kk = 0; kk < 8; ++kk) {
        int c0 = 32 * kk + 8 * oct;
        bf16x8 bfr[2];
#pragma unroll
        for (int nf = 0; nf < 2; ++nf)
            bfr[nf] = *(const bf16x8*)&Xb[(size_t)(tb + 32 * w + 16 * nf + l) * C_ + c0];
#pragma unroll
        for (int mf = 0; mf < 4; ++mf) {
            bf16x8 af = *(const bf16x8*)&SH[(16 * mf + l) * 264 + c0];
#pragma unroll
            for (int nf = 0; nf < 2; ++nf)
                acc[mf][nf] = __builtin_amdgcn_mfma_f32_16x16x32_bf16(af, bfr[nf], acc[mf][nf], 0, 0, 0);
        }
    }

    int head = by / 3, sec = by - 3 * head;
    int bh = bz * NH + head;

    if (sec < 2) {
        float scale = (sec == 0) ? 0.125f * LOG2E : 1.f;
        unsigned short* dst = ((sec == 0) ? q_t : k_t) + (size_t)bh * T_ * CH;
#pragma unroll
        for (int mf = 0; mf < 4; ++mf) {
            float bvs[4];
#pragma unroll
            for (int r = 0; r < 4; ++r) bvs[r] = bias[ob + 16 * mf + 4 * oct + r];
#pragma unroll
            for (int nf = 0; nf < 2; ++nf) {
                int t = tb + 32 * w + 16 * nf + l;
                float v0 = (acc[mf][nf][0] + bvs[0]) * scale;
                float v1 = (acc[mf][nf][1] + bvs[1]) * scale;
                float v2 = (acc[mf][nf][2] + bvs[2]) * scale;
                float v3 = (acc[mf][nf][3] + bvs[3]) * scale;
                uint2 u; u.x = pk2(v0, v1); u.y = pk2(v2, v3);
                *(uint2*)&dst[(size_t)t * CH + 16 * mf + 4 * oct] = u;
            }
        }
    } else {
        __syncthreads();   // reuse SH as Vl[64][136]
#pragma unroll
        for (int mf = 0; mf < 4; ++mf) {
            float bvs[4];
#pragma unroll
            for (int r = 0; r < 4; ++r) bvs[r] = bias[ob + 16 * mf + 4 * oct + r];
#pragma unroll
            for (int nf = 0; nf < 2; ++nf) {
                int tl = 32 * w + 16 * nf + l;
#pragma unroll
                for (int r = 0; r < 4; ++r) {
                    unsigned pv = pk2(acc[mf][nf][r] + bvs[r], 0.f);
                    SH[(16 * mf + 4 * oct + r) * 136 + tl] = (unsigned short)(pv & 0xffffu);
                }
            }
        }
        __syncthreads();
        unsigned short* vdst = v_d + (size_t)bh * CH * T_;
#pragma unroll
        for (int j = 0; j < 4; ++j) {
            int idx = tid + 256 * j;
            int row = idx >> 4, ch = idx & 15;
            *(uint4*)&vdst[(size_t)row * T_ + tb + ch * 8] =
                *(uint4*)&SH[row * 136 + ch * 8];
        }
    }
}

// ---------------------------------------------------------------------------
// Kernel 3: flash attention, XOR-swizzled LDS (stride 64, 16B chunk m of row
// r stored at m^(r&7)) -> bank-floor for staging writes, A-frag reads, and
// the Ps round-trip.  Register-prefetched K/V staging.  No-max softmax.
// grid (T/128, B*NH, SPLIT), block 256.
// ---------------------------------------------------------------------------
__global__ __launch_bounds__(256, 4) void attn_kernel(
    const unsigned short* __restrict__ q_t, const unsigned short* __restrict__ k_t,
    const unsigned short* __restrict__ v_d, unsigned short* __restrict__ Opart,
    float* __restrict__ lbuf) {
    int bh = blockIdx.y;
    int sp = blockIdx.z;
    int t0 = blockIdx.x * 128;
    int tid = threadIdx.x;
    int l = tid & 15, q = (tid >> 4) & 3, w = tid >> 6;
    int lsw = l & 7;                      // row&7 for all frag rows (16sf+l etc.)

    __shared__ __align__(16) unsigned short Kt[64 * 64];   // [s][c] swizzled
    __shared__ __align__(16) unsigned short Vt[64 * 64];   // [c][s] swizzled
    __shared__ __align__(16) unsigned short Ps[128 * 64];  // [t][s] swizzled

    const unsigned short* qb = q_t + (size_t)bh * T_ * CH;
    const unsigned short* kb = k_t + (size_t)bh * T_ * CH;
    const unsigned short* vb = v_d + (size_t)bh * CH * T_;

    bf16x8 qf[2][2];
#pragma unroll
    for (int nf = 0; nf < 2; ++nf) {
        int t = t0 + 32 * w + 16 * nf + l;
#pragma unroll
        for (int kk = 0; kk < 2; ++kk)
            qf[nf][kk] = *(const bf16x8*)&qb[(size_t)t * CH + 32 * kk + 8 * q];
    }

    // staging lane addresses (row srow, chunk ch -> stored at ch^(srow&7))
    int srow = tid >> 3;                  // 0..31
    int sch  = tid & 7;
    int ssw  = (sch ^ (srow & 7)) * 8;    // (srow+32)&7 == srow&7
    const unsigned short* kp0 = kb + (size_t)srow * CH + sch * 8;
    const unsigned short* kp1 = kb + (size_t)(srow + 32) * CH + sch * 8;
    const unsigned short* vp0 = vb + (size_t)srow * T_ + sch * 8;
    const unsigned short* vp1 = vb + (size_t)(srow + 32) * T_ + sch * 8;

    f32x4 O[4][2];
#pragma unroll
    for (int mf = 0; mf < 4; ++mf)
#pragma unroll
        for (int nf = 0; nf < 2; ++nf) O[mf][nf] = (f32x4){0.f, 0.f, 0.f, 0.f};
    float l_run[2] = {0.f, 0.f};

    int s_beg = sp * (T_ / SPLIT);
    int s_end = s_beg + (T_ / SPLIT);

    // prologue prefetch: tile s_beg
    uint4 kreg0 = *(const uint4*)(kp0 + (size_t)s_beg * CH);
    uint4 kreg1 = *(const uint4*)(kp1 + (size_t)s_beg * CH);
    uint4 vreg0 = *(const uint4*)(vp0 + s_beg);
    uint4 vreg1 = *(const uint4*)(vp1 + s_beg);

    for (int s0 = s_beg; s0 < s_end; s0 += 64) {
        // ---- commit prefetched regs to LDS (swizzled) ----
        *(uint4*)&Kt[srow * 64 + ssw]        = kreg0;
        *(uint4*)&Kt[(srow + 32) * 64 + ssw] = kreg1;
        *(uint4*)&Vt[srow * 64 + ssw]        = vreg0;
        *(uint4*)&Vt[(srow + 32) * 64 + ssw] = vreg1;
        __syncthreads();

        // ---- prefetch next tile ----
        int sn = s0 + 64;
        if (sn < s_end) {
            kreg0 = *(const uint4*)(kp0 + (size_t)sn * CH);
            kreg1 = *(const uint4*)(kp1 + (size_t)sn * CH);
            vreg0 = *(const uint4*)(vp0 + sn);
            vreg1 = *(const uint4*)(vp1 + sn);
        }

        // ---- S^T = K^T Q ----
        f32x4 S[4][2];
#pragma unroll
        for (int sf = 0; sf < 4; ++sf) {
            f32x4 a0 = (f32x4){0.f, 0.f, 0.f, 0.f};
            f32x4 a1 = (f32x4){0.f, 0.f, 0.f, 0.f};
#pragma unroll
            for (int kk = 0; kk < 2; ++kk) {
                bf16x8 ka = *(const bf16x8*)
                    &Kt[(16 * sf + l) * 64 + (((4 * kk + q) ^ lsw) * 8)];
                a0 = __builtin_amdgcn_mfma_f32_16x16x32_bf16(ka, qf[0][kk], a0, 0, 0, 0);
                a1 = __builtin_amdgcn_mfma_f32_16x16x32_bf16(ka, qf[1][kk], a1, 0, 0, 0);
            }
            S[sf][0] = a0; S[sf][1] = a1;
        }

        // ---- p = exp2(S), accumulate per-lane l partials ----
#pragma unroll
        for (int nf = 0; nf < 2; ++nf) {
            int trow = 32 * w + 16 * nf + l;
            float lloc = 0.f;
#pragma unroll
            for (int sf = 0; sf < 4; ++sf) {
                float p0 = EXP2(S[sf][nf][0]);
                float p1 = EXP2(S[sf][nf][1]);
                float p2 = EXP2(S[sf][nf][2]);
                float p3 = EXP2(S[sf][nf][3]);
                lloc += (p0 + p1) + (p2 + p3);
                uint2 u; u.x = pk2(p0, p1); u.y = pk2(p2, p3);
                // logical chunk 2sf+(q>>1), half q&1, row trow (trow&7 == lsw)
                *(uint2*)&Ps[trow * 64 + (((2 * sf + (q >> 1)) ^ lsw) * 8)
                             + (q & 1) * 4] = u;
            }
            l_run[nf] += lloc;
        }

        // ---- O^T += V P^T ----
#pragma unroll
        for (int kk = 0; kk < 2; ++kk) {
            bf16x8 pb[2];
#pragma unroll
            for (int nf = 0; nf < 2; ++nf)
                pb[nf] = *(const bf16x8*)
                    &Ps[(32 * w + 16 * nf + l) * 64 + (((4 * kk + q) ^ lsw) * 8)];
#pragma unroll
            for (int mf = 0; mf < 4; ++mf) {
                bf16x8 va = *(const bf16x8*)
                    &Vt[(16 * mf + l) * 64 + (((4 * kk + q) ^ lsw) * 8)];
#pragma unroll
                for (int nf = 0; nf < 2; ++nf)
                    O[mf][nf] = __builtin_amdgcn_mfma_f32_16x16x32_bf16(va, pb[nf], O[mf][nf], 0, 0, 0);
            }
        }
        __syncthreads();
    }

    // ---- final l reduce + store normalized partials bf16 ----
#pragma unroll
    for (int nf = 0; nf < 2; ++nf) {
        float lt = l_run[nf];
        lt += __shfl_xor(lt, 16);
        lt += __shfl_xor(lt, 32);
        float inv = 1.f / lt;
        int t = t0 + 32 * w + 16 * nf + l;
        size_t row = (size_t)(sp * 8 + bh) * T_ + t;
        unsigned short* op = Opart + row * CH;
#pragma unroll
        for (int mf = 0; mf < 4; ++mf) {
            uint2 u;
            u.x = pk2(O[mf][nf][0] * inv, O[mf][nf][1] * inv);
            u.y = pk2(O[mf][nf][2] * inv, O[mf][nf][3] * inv);
            *(uint2*)&op[16 * mf + 4 * q] = u;
        }
        if (q == 0) lbuf[row] = lt;
    }
}

// ---------------------------------------------------------------------------
// Kernel 4: combine SPLIT partials -> a_t[b][t][c] bf16.  Weights l_sp/Σl.
// ---------------------------------------------------------------------------
__global__ __launch_bounds__(256) void combine_kernel(
    const unsigned short* __restrict__ Opart, const float* __restrict__ lbuf,
    unsigned short* __restrict__ a_t) {
    int bx = blockIdx.x;
    int bh = bx >> 6;
    int tblk = bx & 63;
    int tid = threadIdx.x;
    int t = tblk * 64 + (tid >> 2);
    int sub = tid & 3;

    float lw[SPLIT];
    size_t rows[SPLIT];
    float lsum = 0.f;
#pragma unroll
    for (int sp = 0; sp < SPLIT; ++sp) {
        rows[sp] = (size_t)(sp * 8 + bh) * T_ + t;
        lw[sp] = lbuf[rows[sp]];
        lsum += lw[sp];
    }
    float inv = 1.f / lsum;

    float o[16];
#pragma unroll
    for (int i = 0; i < 16; ++i) o[i] = 0.f;
#pragma unroll
    for (int sp = 0; sp < SPLIT; ++sp) {
        float s = lw[sp] * inv;
        const unsigned short* p = Opart + rows[sp] * CH + sub * 16;
        uint4 u0 = *(const uint4*)p;
        uint4 u1 = *(const uint4*)(p + 8);
        unsigned us[8] = {u0.x, u0.y, u0.z, u0.w, u1.x, u1.y, u1.z, u1.w};
#pragma unroll
        for (int j = 0; j < 8; ++j) {
            o[2 * j]     += bf2f((unsigned short)(us[j] & 0xffffu)) * s;
            o[2 * j + 1] += bf2f((unsigned short)(us[j] >> 16)) * s;
        }
    }

    int batch = bh >> 2, h = bh & 3;
    unsigned short* dst = a_t + ((size_t)batch * T_ + t) * C_ + h * CH + sub * 16;
    uint4 u0, u1;
    u0.x = pk2(o[0], o[1]);   u0.y = pk2(o[2], o[3]);
    u0.z = pk2(o[4], o[5]);   u0.w = pk2(o[6], o[7]);
    u1.x = pk2(o[8], o[9]);   u1.y = pk2(o[10], o[11]);
    u1.z = pk2(o[12], o[13]); u1.w = pk2(o[14], o[15]);
    *(uint4*)dst = u0;
    *(uint4*)(dst + 8) = u1;
}

// ---------------------------------------------------------------------------
// Kernel 5: proj GEMM + bias + residual -> fp32 out.  W staged in LDS.
// 64-t tiles: grid (64, 4, 2) = 512 blocks (2/CU).  Wave owns 16 t.
// ---------------------------------------------------------------------------
__global__ __launch_bounds__(256) void proj_gemm_kernel(
    const unsigned short* __restrict__ Wb, const float* __restrict__ bias,
    const unsigned short* __restrict__ At, const float* __restrict__ xres,
    float* __restrict__ out) {
    int tb = blockIdx.x * 64;
    int ob = blockIdx.y * 64;
    int bz = blockIdx.z;
    int tid = threadIdx.x;
    int l = tid & 15, oct = (tid >> 4) & 3, w = tid >> 6;

    __shared__ __align__(16) unsigned short SH[64 * 264];

#pragma unroll
    for (int j = 0; j < 8; ++j) {
        int idx = tid + 256 * j;
        int row = idx >> 5, ch = idx & 31;
        *(uint4*)&SH[row * 264 + ch * 8] =
            *(const uint4*)&Wb[(size_t)(ob + row) * C_ + ch * 8];
    }
    __syncthreads();

    const unsigned short* Ab = At + (size_t)bz * T_ * C_;
    int t = tb + 16 * w + l;

    f32x4 acc[4];
#pragma unroll
    for (int mf = 0; mf < 4; ++mf) acc[mf] = (f32x4){0.f, 0.f, 0.f, 0.f};

#pragma unroll
    for (int kk = 0; kk < 8; ++kk) {
        int c0 = 32 * kk + 8 * oct;
        bf16x8 bfr = *(const bf16x8*)&Ab[(size_t)t * C_ + c0];
#pragma unroll
        for (int mf = 0; mf < 4; ++mf) {
            bf16x8 af = *(const bf16x8*)&SH[(16 * mf + l) * 264 + c0];
            acc[mf] = __builtin_amdgcn_mfma_f32_16x16x32_bf16(af, bfr, acc[mf], 0, 0, 0);
        }
    }

#pragma unroll
    for (int mf = 0; mf < 4; ++mf) {
#pragma unroll
        for (int r = 0; r < 4; ++r) {
            int o = ob + 16 * mf + 4 * oct + r;
            size_t idx = ((size_t)bz * C_ + o) * T_ + t;
            out[idx] = acc[mf][r] + bias[o] + xres[idx];
        }
    }
}

// ---------------------------------------------------------------------------
extern "C" void kernel_launch(void* const* d_in, const int* in_sizes, int n_in,
                              void* d_out, int out_size, void* d_ws, size_t ws_size,
                              hipStream_t stream) {
    const float* x      = (const float*)d_in[0];
    const float* norm_w = (const float*)d_in[1];
    const float* norm_b = (const float*)d_in[2];
    const float* qkv_w  = (const float*)d_in[3];
    const float* qkv_b  = (const float*)d_in[4];
    const float* proj_w = (const float*)d_in[5];
    const float* proj_b = (const float*)d_in[6];
    float* out = (float*)d_out;

    char* p = (char*)d_ws;
    unsigned short* xnT = (unsigned short*)p; p += (size_t)B_ * T_ * C_ * 2;        // 4 MB
    unsigned short* qwb = (unsigned short*)p; p += (size_t)K3C * C_ * 2;            // 384 KB
    unsigned short* pwb = (unsigned short*)p; p += (size_t)C_ * C_ * 2;             // 128 KB
    unsigned short* q_t = (unsigned short*)p; p += (size_t)B_ * NH * T_ * CH * 2;   // 4 MB
    unsigned short* k_t = (unsigned short*)p; p += (size_t)B_ * NH * T_ * CH * 2;   // 4 MB
    unsigned short* v_d = (unsigned short*)p; p += (size_t)B_ * NH * T_ * CH * 2;   // 4 MB
    unsigned short* Opart = (unsigned short*)p; p += (size_t)SPLIT * 8 * T_ * CH * 2; // 16 MB
    float* lbuf         = (float*)p;          p += (size_t)SPLIT * 8 * T_ * 4;      // 512 KB
    unsigned short* a_t = (unsigned short*)p; p += (size_t)B_ * T_ * C_ * 2;        // 4 MB
    float* stat         = (float*)p;          p += (size_t)NSTAT * 2 * 4;           // 4 KB

    pre_kernel<<<dim3(NSTAT + NCVT), dim3(256), 0, stream>>>(
        x, stat, qkv_w, proj_w, qwb, pwb);
    gn_apply_kernel<<<dim3(B_ * GRP, GSL), dim3(256), 0, stream>>>(
        x, stat, norm_w, norm_b, xnT);
    qkv_gemm_kernel<<<dim3(T_ / 128, 12, B_), dim3(256), 0, stream>>>(
        qwb, qkv_b, xnT, q_t, k_t, v_d);
    attn_kernel<<<dim3(T_ / 128, B_ * NH, SPLIT), dim3(256), 0, stream>>>(
        q_t, k_t, v_d, Opart, lbuf);
    combine_kernel<<<dim3(B_ * NH * (T_ / 64)), dim3(256), 0, stream>>>(Opart, lbuf, a_t);
    proj_gemm_kernel<<<dim3(T_ / 64, C_ / 64, B_), dim3(256), 0, stream>>>(
        pwb, proj_b, a_t, x, out);
}

// Round 12
// 144.011 us; speedup vs baseline: 1.2840x; 1.2840x over previous
//
#include <hip/hip_runtime.h>
#include <hip/hip_bf16.h>

// Problem constants
#define B_    2
#define C_    256
#define T_    4096
#define GRP   32
#define CPG   8
#define NH    4
#define CH    64
#define K3C   768
#define SPLIT 4
#define GSL   8          // group-norm slices per group
#define NSTAT (B_ * GRP * GSL)   // 512
#define NCVT  128
#define LOG2E 1.4426950408889634f

typedef __attribute__((ext_vector_type(8))) short bf16x8;
typedef __attribute__((ext_vector_type(4))) float f32x4;

#if __has_builtin(__builtin_amdgcn_exp2f)
#define EXP2(x) __builtin_amdgcn_exp2f(x)
#else
#define EXP2(x) exp2f(x)
#endif

__device__ __forceinline__ unsigned pk2(float a, float b) {
    __hip_bfloat162 h = __float22bfloat162_rn(make_float2(a, b));
    union { __hip_bfloat162 h2; unsigned u; } cv; cv.h2 = h;
    return cv.u;
}
__device__ __forceinline__ float bf2f(unsigned short u) {
    return __uint_as_float((unsigned)u << 16);
}

// ---------------------------------------------------------------------------
// Kernel 0: fused GroupNorm stats (blocks 0..511) + weight cvt (512..639).
// ---------------------------------------------------------------------------
__global__ __launch_bounds__(256) void pre_kernel(
    const float* __restrict__ x, float* __restrict__ stat,
    const float* __restrict__ qw, const float* __restrict__ pw,
    unsigned short* __restrict__ qwb, unsigned short* __restrict__ pwb) {
    int bid = blockIdx.x;
    int tid = threadIdx.x;
    if (bid < NSTAT) {
        int bg = bid >> 3, sl = bid & 7;
        const int SLN = CPG * T_ / GSL;        // 4096
        const float* xp = x + (size_t)bg * CPG * T_ + (size_t)sl * SLN;
        float s = 0.f, s2 = 0.f;
        for (int i = tid * 4; i < SLN; i += 1024) {
            float4 v = *(const float4*)&xp[i];
            s  += (v.x + v.y) + (v.z + v.w);
            s2 += (v.x * v.x + v.y * v.y) + (v.z * v.z + v.w * v.w);
        }
        for (int off = 32; off > 0; off >>= 1) {
            s  += __shfl_down(s,  off);
            s2 += __shfl_down(s2, off);
        }
        __shared__ float rs[4], rs2[4];
        int wid = tid >> 6;
        if ((tid & 63) == 0) { rs[wid] = s; rs2[wid] = s2; }
        __syncthreads();
        if (tid == 0) {
            stat[bid * 2]     = (rs[0] + rs[1]) + (rs[2] + rs[3]);
            stat[bid * 2 + 1] = (rs2[0] + rs2[1]) + (rs2[2] + rs2[3]);
        }
    } else {
        int i = (bid - NSTAT) * 256 + tid;
        const int n1 = K3C * C_ / 8;
        const float* src; unsigned short* dst;
        if (i < n1) { src = qw + 8 * i; dst = qwb + 8 * i; }
        else { int j = i - n1; src = pw + 8 * j; dst = pwb + 8 * j; }
        float4 a = *(const float4*)src;
        float4 b = *(const float4*)(src + 4);
        uint4 u;
        u.x = pk2(a.x, a.y); u.y = pk2(a.z, a.w);
        u.z = pk2(b.x, b.y); u.w = pk2(b.z, b.w);
        *(uint4*)dst = u;
    }
}

// ---------------------------------------------------------------------------
// Kernel 1: GroupNorm apply -> bf16 transposed xnT[b][t][c].
// ---------------------------------------------------------------------------
__global__ __launch_bounds__(256) void gn_apply_kernel(
    const float* __restrict__ x, const float* __restrict__ stat,
    const float* __restrict__ w, const float* __restrict__ b,
    unsigned short* __restrict__ xnT) {
    int bg = blockIdx.x, sl = blockIdx.y;
    int batch = bg / GRP, g = bg % GRP;
    const float* xp = x + (size_t)bg * CPG * T_;
    int tid = threadIdx.x;

    float s = 0.f, s2 = 0.f;
#pragma unroll
    for (int i = 0; i < GSL; ++i) {
        s  += stat[(bg * GSL + i) * 2];
        s2 += stat[(bg * GSL + i) * 2 + 1];
    }
    float inv_n = 1.f / (float)(CPG * T_);
    float mean = s * inv_n;
    float var  = s2 * inv_n - mean * mean;
    float inv  = rsqrtf(var + 1e-5f);

    float wv[8], bv[8];
#pragma unroll
    for (int j = 0; j < 8; j++) {
        float ww = w[g * CPG + j] * inv;
        wv[j] = ww;
        bv[j] = b[g * CPG + j] - mean * ww;
    }
    unsigned short* op = xnT + (size_t)batch * T_ * C_ + g * CPG;
    int t0 = sl * (T_ / GSL);
#pragma unroll
    for (int rep = 0; rep < 2; ++rep) {
        int t = t0 + rep * 256 + tid;
        float v[8];
#pragma unroll
        for (int j = 0; j < 8; j++) v[j] = xp[(size_t)j * T_ + t] * wv[j] + bv[j];
        uint4 u;
        u.x = pk2(v[0], v[1]); u.y = pk2(v[2], v[3]);
        u.z = pk2(v[4], v[5]); u.w = pk2(v[6], v[7]);
        *(uint4*)&op[(size_t)t * C_] = u;
    }
}

// ---------------------------------------------------------------------------
// Kernel 2: QKV GEMM.  W-tile staged in LDS once; X B-frags direct-global.
// grid(32,12,2), block 256.  Epilogue: q/k -> [t][c] (q pre-scaled), v -> v_d.
// ---------------------------------------------------------------------------
__global__ __launch_bounds__(256) void qkv_gemm_kernel(
    const unsigned short* __restrict__ Wb, const float* __restrict__ bias,
    const unsigned short* __restrict__ Xt, unsigned short* __restrict__ q_t,
    unsigned short* __restrict__ k_t, unsigned short* __restrict__ v_d) {
    int tb = blockIdx.x * 128;
    int by = blockIdx.y;
    int bz = blockIdx.z;
    int ob = by * 64;
    int tid = threadIdx.x;
    int l = tid & 15, oct = (tid >> 4) & 3, w = tid >> 6;

    __shared__ __align__(16) unsigned short SH[64 * 264];

#pragma unroll
    for (int j = 0; j < 8; ++j) {
        int idx = tid + 256 * j;
        int row = idx >> 5, ch = idx & 31;
        *(uint4*)&SH[row * 264 + ch * 8] =
            *(const uint4*)&Wb[(size_t)(ob + row) * C_ + ch * 8];
    }
    __syncthreads();

    const unsigned short* Xb = Xt + (size_t)bz * T_ * C_;

    f32x4 acc[4][2];
#pragma unroll
    for (int mf = 0; mf < 4; ++mf)
#pragma unroll
        for (int nf = 0; nf < 2; ++nf) acc[mf][nf] = (f32x4){0.f, 0.f, 0.f, 0.f};

#pragma unroll
    for (int kk = 0; kk < 8; ++kk) {
        int c0 = 32 * kk + 8 * oct;
        bf16x8 bfr[2];
#pragma unroll
        for (int nf = 0; nf < 2; ++nf)
            bfr[nf] = *(const bf16x8*)&Xb[(size_t)(tb + 32 * w + 16 * nf + l) * C_ + c0];
#pragma unroll
        for (int mf = 0; mf < 4; ++mf) {
            bf16x8 af = *(const bf16x8*)&SH[(16 * mf + l) * 264 + c0];
#pragma unroll
            for (int nf = 0; nf < 2; ++nf)
                acc[mf][nf] = __builtin_amdgcn_mfma_f32_16x16x32_bf16(af, bfr[nf], acc[mf][nf], 0, 0, 0);
        }
    }

    int head = by / 3, sec = by - 3 * head;
    int bh = bz * NH + head;

    if (sec < 2) {
        float scale = (sec == 0) ? 0.125f * LOG2E : 1.f;
        unsigned short* dst = ((sec == 0) ? q_t : k_t) + (size_t)bh * T_ * CH;
#pragma unroll
        for (int mf = 0; mf < 4; ++mf) {
            float bvs[4];
#pragma unroll
            for (int r = 0; r < 4; ++r) bvs[r] = bias[ob + 16 * mf + 4 * oct + r];
#pragma unroll
            for (int nf = 0; nf < 2; ++nf) {
                int t = tb + 32 * w + 16 * nf + l;
                float v0 = (acc[mf][nf][0] + bvs[0]) * scale;
                float v1 = (acc[mf][nf][1] + bvs[1]) * scale;
                float v2 = (acc[mf][nf][2] + bvs[2]) * scale;
                float v3 = (acc[mf][nf][3] + bvs[3]) * scale;
                uint2 u; u.x = pk2(v0, v1); u.y = pk2(v2, v3);
                *(uint2*)&dst[(size_t)t * CH + 16 * mf + 4 * oct] = u;
            }
        }
    } else {
        __syncthreads();   // reuse SH as Vl[64][136]
#pragma unroll
        for (int mf = 0; mf < 4; ++mf) {
            float bvs[4];
#pragma unroll
            for (int r = 0; r < 4; ++r) bvs[r] = bias[ob + 16 * mf + 4 * oct + r];
#pragma unroll
            for (int nf = 0; nf < 2; ++nf) {
                int tl = 32 * w + 16 * nf + l;
#pragma unroll
                for (int r = 0; r < 4; ++r) {
                    unsigned pv = pk2(acc[mf][nf][r] + bvs[r], 0.f);
                    SH[(16 * mf + 4 * oct + r) * 136 + tl] = (unsigned short)(pv & 0xffffu);
                }
            }
        }
        __syncthreads();
        unsigned short* vdst = v_d + (size_t)bh * CH * T_;
#pragma unroll
        for (int j = 0; j < 4; ++j) {
            int idx = tid + 256 * j;
            int row = idx >> 4, ch = idx & 15;
            *(uint4*)&vdst[(size_t)row * T_ + tb + ch * 8] =
                *(uint4*)&SH[row * 136 + ch * 8];
        }
    }
}

// ---------------------------------------------------------------------------
// Kernel 3: flash attention, XOR-swizzled LDS (stride 64; 16B chunk m of row
// r stored at m^(r&7)), NO register prefetch (R11 spill post-mortem: prefetch
// regs + swizzle arithmetic caused scratch spills, 115 MB/launch).
// grid (T/128, B*NH, SPLIT), block 256.  No-max softmax (log2 domain).
// ---------------------------------------------------------------------------
__global__ __launch_bounds__(256, 4) void attn_kernel(
    const unsigned short* __restrict__ q_t, const unsigned short* __restrict__ k_t,
    const unsigned short* __restrict__ v_d, unsigned short* __restrict__ Opart,
    float* __restrict__ lbuf) {
    int bh = blockIdx.y;
    int sp = blockIdx.z;
    int t0 = blockIdx.x * 128;
    int tid = threadIdx.x;
    int l = tid & 15, q = (tid >> 4) & 3, w = tid >> 6;
    int lsw = l & 7;                      // row&7 for all frag rows

    __shared__ __align__(16) unsigned short Kt[64 * 64];   // [s][c] swizzled
    __shared__ __align__(16) unsigned short Vt[64 * 64];   // [c][s] swizzled
    __shared__ __align__(16) unsigned short Ps[128 * 64];  // [t][s] swizzled

    const unsigned short* qb = q_t + (size_t)bh * T_ * CH;
    const unsigned short* kb = k_t + (size_t)bh * T_ * CH;
    const unsigned short* vb = v_d + (size_t)bh * CH * T_;

    bf16x8 qf[2][2];
#pragma unroll
    for (int nf = 0; nf < 2; ++nf) {
        int t = t0 + 32 * w + 16 * nf + l;
#pragma unroll
        for (int kk = 0; kk < 2; ++kk)
            qf[nf][kk] = *(const bf16x8*)&qb[(size_t)t * CH + 32 * kk + 8 * q];
    }

    // staging lane addresses (row srow(+32), chunk sch -> stored at sch^(srow&7))
    int srow = tid >> 3;                  // 0..31
    int sch  = tid & 7;
    int ssw  = (sch ^ (srow & 7)) * 8;    // (srow+32)&7 == srow&7

    f32x4 O[4][2];
#pragma unroll
    for (int mf = 0; mf < 4; ++mf)
#pragma unroll
        for (int nf = 0; nf < 2; ++nf) O[mf][nf] = (f32x4){0.f, 0.f, 0.f, 0.f};
    float l_run[2] = {0.f, 0.f};

    int s_beg = sp * (T_ / SPLIT);
    int s_end = s_beg + (T_ / SPLIT);

    for (int s0 = s_beg; s0 < s_end; s0 += 64) {
        // ---- stage K[s][c] and V[c][s] (immediate, swizzled dest) ----
        *(uint4*)&Kt[srow * 64 + ssw] =
            *(const uint4*)&kb[(size_t)(s0 + srow) * CH + sch * 8];
        *(uint4*)&Kt[(srow + 32) * 64 + ssw] =
            *(const uint4*)&kb[(size_t)(s0 + srow + 32) * CH + sch * 8];
        *(uint4*)&Vt[srow * 64 + ssw] =
            *(const uint4*)&vb[(size_t)srow * T_ + s0 + sch * 8];
        *(uint4*)&Vt[(srow + 32) * 64 + ssw] =
            *(const uint4*)&vb[(size_t)(srow + 32) * T_ + s0 + sch * 8];
        __syncthreads();

        // ---- S^T = K^T Q ----
        f32x4 S[4][2];
#pragma unroll
        for (int sf = 0; sf < 4; ++sf) {
            f32x4 a0 = (f32x4){0.f, 0.f, 0.f, 0.f};
            f32x4 a1 = (f32x4){0.f, 0.f, 0.f, 0.f};
#pragma unroll
            for (int kk = 0; kk < 2; ++kk) {
                bf16x8 ka = *(const bf16x8*)
                    &Kt[(16 * sf + l) * 64 + (((4 * kk + q) ^ lsw) * 8)];
                a0 = __builtin_amdgcn_mfma_f32_16x16x32_bf16(ka, qf[0][kk], a0, 0, 0, 0);
                a1 = __builtin_amdgcn_mfma_f32_16x16x32_bf16(ka, qf[1][kk], a1, 0, 0, 0);
            }
            S[sf][0] = a0; S[sf][1] = a1;
        }

        // ---- p = exp2(S), accumulate per-lane l partials ----
#pragma unroll
        for (int nf = 0; nf < 2; ++nf) {
            int trow = 32 * w + 16 * nf + l;
            float lloc = 0.f;
#pragma unroll
            for (int sf = 0; sf < 4; ++sf) {
                float p0 = EXP2(S[sf][nf][0]);
                float p1 = EXP2(S[sf][nf][1]);
                float p2 = EXP2(S[sf][nf][2]);
                float p3 = EXP2(S[sf][nf][3]);
                lloc += (p0 + p1) + (p2 + p3);
                uint2 u; u.x = pk2(p0, p1); u.y = pk2(p2, p3);
                // logical chunk 2sf+(q>>1), half q&1, row trow (trow&7 == lsw)
                *(uint2*)&Ps[trow * 64 + (((2 * sf + (q >> 1)) ^ lsw) * 8)
                             + (q & 1) * 4] = u;
            }
            l_run[nf] += lloc;
        }

        // ---- O^T += V P^T ----
#pragma unroll
        for (int kk = 0; kk < 2; ++kk) {
            bf16x8 pb[2];
#pragma unroll
            for (int nf = 0; nf < 2; ++nf)
                pb[nf] = *(const bf16x8*)
                    &Ps[(32 * w + 16 * nf + l) * 64 + (((4 * kk + q) ^ lsw) * 8)];
#pragma unroll
            for (int mf = 0; mf < 4; ++mf) {
                bf16x8 va = *(const bf16x8*)
                    &Vt[(16 * mf + l) * 64 + (((4 * kk + q) ^ lsw) * 8)];
#pragma unroll
                for (int nf = 0; nf < 2; ++nf)
                    O[mf][nf] = __builtin_amdgcn_mfma_f32_16x16x32_bf16(va, pb[nf], O[mf][nf], 0, 0, 0);
            }
        }
        __syncthreads();
    }

    // ---- final l reduce + store normalized partials bf16 ----
#pragma unroll
    for (int nf = 0; nf < 2; ++nf) {
        float lt = l_run[nf];
        lt += __shfl_xor(lt, 16);
        lt += __shfl_xor(lt, 32);
        float inv = 1.f / lt;
        int t = t0 + 32 * w + 16 * nf + l;
        size_t row = (size_t)(sp * 8 + bh) * T_ + t;
        unsigned short* op = Opart + row * CH;
#pragma unroll
        for (int mf = 0; mf < 4; ++mf) {
            uint2 u;
            u.x = pk2(O[mf][nf][0] * inv, O[mf][nf][1] * inv);
            u.y = pk2(O[mf][nf][2] * inv, O[mf][nf][3] * inv);
            *(uint2*)&op[16 * mf + 4 * q] = u;
        }
        if (q == 0) lbuf[row] = lt;
    }
}

// ---------------------------------------------------------------------------
// Kernel 4: combine SPLIT partials -> a_t[b][t][c] bf16.  Weights l_sp/Σl.
// ---------------------------------------------------------------------------
__global__ __launch_bounds__(256) void combine_kernel(
    const unsigned short* __restrict__ Opart, const float* __restrict__ lbuf,
    unsigned short* __restrict__ a_t) {
    int bx = blockIdx.x;
    int bh = bx >> 6;
    int tblk = bx & 63;
    int tid = threadIdx.x;
    int t = tblk * 64 + (tid >> 2);
    int sub = tid & 3;

    float lw[SPLIT];
    size_t rows[SPLIT];
    float lsum = 0.f;
#pragma unroll
    for (int sp = 0; sp < SPLIT; ++sp) {
        rows[sp] = (size_t)(sp * 8 + bh) * T_ + t;
        lw[sp] = lbuf[rows[sp]];
        lsum += lw[sp];
    }
    float inv = 1.f / lsum;

    float o[16];
#pragma unroll
    for (int i = 0; i < 16; ++i) o[i] = 0.f;
#pragma unroll
    for (int sp = 0; sp < SPLIT; ++sp) {
        float s = lw[sp] * inv;
        const unsigned short* p = Opart + rows[sp] * CH + sub * 16;
        uint4 u0 = *(const uint4*)p;
        uint4 u1 = *(const uint4*)(p + 8);
        unsigned us[8] = {u0.x, u0.y, u0.z, u0.w, u1.x, u1.y, u1.z, u1.w};
#pragma unroll
        for (int j = 0; j < 8; ++j) {
            o[2 * j]     += bf2f((unsigned short)(us[j] & 0xffffu)) * s;
            o[2 * j + 1] += bf2f((unsigned short)(us[j] >> 16)) * s;
        }
    }

    int batch = bh >> 2, h = bh & 3;
    unsigned short* dst = a_t + ((size_t)batch * T_ + t) * C_ + h * CH + sub * 16;
    uint4 u0, u1;
    u0.x = pk2(o[0], o[1]);   u0.y = pk2(o[2], o[3]);
    u0.z = pk2(o[4], o[5]);   u0.w = pk2(o[6], o[7]);
    u1.x = pk2(o[8], o[9]);   u1.y = pk2(o[10], o[11]);
    u1.z = pk2(o[12], o[13]); u1.w = pk2(o[14], o[15]);
    *(uint4*)dst = u0;
    *(uint4*)(dst + 8) = u1;
}

// ---------------------------------------------------------------------------
// Kernel 5: proj GEMM + bias + residual -> fp32 out.  W staged in LDS.
// 64-t tiles: grid (64, 4, 2) = 512 blocks (2/CU).  Wave owns 16 t.
// ---------------------------------------------------------------------------
__global__ __launch_bounds__(256) void proj_gemm_kernel(
    const unsigned short* __restrict__ Wb, const float* __restrict__ bias,
    const unsigned short* __restrict__ At, const float* __restrict__ xres,
    float* __restrict__ out) {
    int tb = blockIdx.x * 64;
    int ob = blockIdx.y * 64;
    int bz = blockIdx.z;
    int tid = threadIdx.x;
    int l = tid & 15, oct = (tid >> 4) & 3, w = tid >> 6;

    __shared__ __align__(16) unsigned short SH[64 * 264];

#pragma unroll
    for (int j = 0; j < 8; ++j) {
        int idx = tid + 256 * j;
        int row = idx >> 5, ch = idx & 31;
        *(uint4*)&SH[row * 264 + ch * 8] =
            *(const uint4*)&Wb[(size_t)(ob + row) * C_ + ch * 8];
    }
    __syncthreads();

    const unsigned short* Ab = At + (size_t)bz * T_ * C_;
    int t = tb + 16 * w + l;

    f32x4 acc[4];
#pragma unroll
    for (int mf = 0; mf < 4; ++mf) acc[mf] = (f32x4){0.f, 0.f, 0.f, 0.f};

#pragma unroll
    for (int kk = 0; kk < 8; ++kk) {
        int c0 = 32 * kk + 8 * oct;
        bf16x8 bfr = *(const bf16x8*)&Ab[(size_t)t * C_ + c0];
#pragma unroll
        for (int mf = 0; mf < 4; ++mf) {
            bf16x8 af = *(const bf16x8*)&SH[(16 * mf + l) * 264 + c0];
            acc[mf] = __builtin_amdgcn_mfma_f32_16x16x32_bf16(af, bfr, acc[mf], 0, 0, 0);
        }
    }

#pragma unroll
    for (int mf = 0; mf < 4; ++mf) {
#pragma unroll
        for (int r = 0; r < 4; ++r) {
            int o = ob + 16 * mf + 4 * oct + r;
            size_t idx = ((size_t)bz * C_ + o) * T_ + t;
            out[idx] = acc[mf][r] + bias[o] + xres[idx];
        }
    }
}

// ---------------------------------------------------------------------------
extern "C" void kernel_launch(void* const* d_in, const int* in_sizes, int n_in,
                              void* d_out, int out_size, void* d_ws, size_t ws_size,
                              hipStream_t stream) {
    const float* x      = (const float*)d_in[0];
    const float* norm_w = (const float*)d_in[1];
    const float* norm_b = (const float*)d_in[2];
    const float* qkv_w  = (const float*)d_in[3];
    const float* qkv_b  = (const float*)d_in[4];
    const float* proj_w = (const float*)d_in[5];
    const float* proj_b = (const float*)d_in[6];
    float* out = (float*)d_out;

    char* p = (char*)d_ws;
    unsigned short* xnT = (unsigned short*)p; p += (size_t)B_ * T_ * C_ * 2;        // 4 MB
    unsigned short* qwb = (unsigned short*)p; p += (size_t)K3C * C_ * 2;            // 384 KB
    unsigned short* pwb = (unsigned short*)p; p += (size_t)C_ * C_ * 2;             // 128 KB
    unsigned short* q_t = (unsigned short*)p; p += (size_t)B_ * NH * T_ * CH * 2;   // 4 MB
    unsigned short* k_t = (unsigned short*)p; p += (size_t)B_ * NH * T_ * CH * 2;   // 4 MB
    unsigned short* v_d = (unsigned short*)p; p += (size_t)B_ * NH * T_ * CH * 2;   // 4 MB
    unsigned short* Opart = (unsigned short*)p; p += (size_t)SPLIT * 8 * T_ * CH * 2; // 16 MB
    float* lbuf         = (float*)p;          p += (size_t)SPLIT * 8 * T_ * 4;      // 512 KB
    unsigned short* a_t = (unsigned short*)p; p += (size_t)B_ * T_ * C_ * 2;        // 4 MB
    float* stat         = (float*)p;          p += (size_t)NSTAT * 2 * 4;           // 4 KB

    pre_kernel<<<dim3(NSTAT + NCVT), dim3(256), 0, stream>>>(
        x, stat, qkv_w, proj_w, qwb, pwb);
    gn_apply_kernel<<<dim3(B_ * GRP, GSL), dim3(256), 0, stream>>>(
        x, stat, norm_w, norm_b, xnT);
    qkv_gemm_kernel<<<dim3(T_ / 128, 12, B_), dim3(256), 0, stream>>>(
        qwb, qkv_b, xnT, q_t, k_t, v_d);
    attn_kernel<<<dim3(T_ / 128, B_ * NH, SPLIT), dim3(256), 0, stream>>>(
        q_t, k_t, v_d, Opart, lbuf);
    combine_kernel<<<dim3(B_ * NH * (T_ / 64)), dim3(256), 0, stream>>>(Opart, lbuf, a_t);
    proj_gemm_kernel<<<dim3(T_ / 64, C_ / 64, B_), dim3(256), 0, stream>>>(
        pwb, proj_b, a_t, x, out);
}